// Round 3
// baseline (332.520 us; speedup 1.0000x reference)
//
#include <hip/hip_runtime.h>
#include <hip/hip_bf16.h>

#define B_ 4
#define T_ 4096
#define C_ 1024
#define H_ 64

typedef __bf16 bf16x8 __attribute__((ext_vector_type(8)));
typedef float f32x4 __attribute__((ext_vector_type(4)));
typedef unsigned short u16x8 __attribute__((ext_vector_type(8)));

union Frag8 { uint4 u; bf16x8 b; u16x8 s; };

__device__ inline unsigned short bfbits(float f) {
  union { __hip_bfloat16 h; unsigned short u; } cv;
  cv.h = __float2bfloat16(f);
  return cv.u;
}

__device__ inline bf16x8 ldb8(const unsigned short* p) {
  Frag8 f; f.u = *(const uint4*)p; return f.b;
}

__device__ inline bf16x8 asbf(uint4 u) { Frag8 f; f.u = u; return f.b; }

__device__ inline Frag8 packA(float4 a0, float4 a1) {
  Frag8 af;
  af.s[0] = bfbits(a0.x); af.s[1] = bfbits(a0.y);
  af.s[2] = bfbits(a0.z); af.s[3] = bfbits(a0.w);
  af.s[4] = bfbits(a1.x); af.s[5] = bfbits(a1.y);
  af.s[6] = bfbits(a1.z); af.s[7] = bfbits(a1.w);
  return af;
}

// ---------------- k0: convert W (3 x [64,1024] fp32) to bf16 ----------------
__global__ __launch_bounds__(256) void wconv(const float* __restrict__ Wq,
                                             const float* __restrict__ Wk,
                                             const float* __restrict__ Wv,
                                             unsigned short* __restrict__ Wb) {
  int i = blockIdx.x * 256 + threadIdx.x;        // 192 blocks -> 49152 threads
  size_t e = (size_t)i * 4;                      // element index in [0, 196608)
  const float* src = (e < 65536) ? (Wq + e)
                   : (e < 131072 ? (Wk + (e - 65536)) : (Wv + (e - 131072)));
  float4 v = *(const float4*)src;
  unsigned long long o =
      (unsigned long long)bfbits(v.x)
    | ((unsigned long long)bfbits(v.y) << 16)
    | ((unsigned long long)bfbits(v.z) << 32)
    | ((unsigned long long)bfbits(v.w) << 48);
  *(unsigned long long*)(Wb + e) = o;
}

// ---------------- k1: QKV projection GEMM (bf16 MFMA) ----------------
// out[m][h] = sum_c x[m][c] * W[h][c];  M=16384, K=1024, N=192 (Q|K|V)
// Block = 16 rows, 4 waves x 48 cols. Two-slot software pipeline keeps 10
// loads in flight (VGPR=20 last round => compiler had serialized every load).
__global__ __launch_bounds__(256) void qkv_proj(const float* __restrict__ x,
                                                const unsigned short* __restrict__ Wb,
                                                unsigned short* __restrict__ qkv,
                                                unsigned short* __restrict__ Vt) {
  const int lane = threadIdx.x & 63;
  const int wave = threadIdx.x >> 6;
  const int q16 = lane & 15, quad = lane >> 4;
  const size_t row0 = (size_t)blockIdx.x * 16;
  const float* xp = x + (row0 + q16) * C_ + quad * 8;

  const unsigned short* wp0;
  const unsigned short* wp1;
  const unsigned short* wp2;
  {
    int g0 = wave * 48, g1 = g0 + 16, g2 = g0 + 32;
    wp0 = Wb + (size_t)(g0 >> 6) * 65536 + (size_t)((g0 & 63) + q16) * C_ + quad * 8;
    wp1 = Wb + (size_t)(g1 >> 6) * 65536 + (size_t)((g1 & 63) + q16) * C_ + quad * 8;
    wp2 = Wb + (size_t)(g2 >> 6) * 65536 + (size_t)((g2 & 63) + q16) * C_ + quad * 8;
  }

  f32x4 acc0 = {}, acc1 = {}, acc2 = {};

  // preload slots A (c=0) and B (c=32)
  float4 a0A = *(const float4*)(xp + 0),  a1A = *(const float4*)(xp + 4);
  uint4  w0A = *(const uint4*)(wp0 + 0),  w1A = *(const uint4*)(wp1 + 0),  w2A = *(const uint4*)(wp2 + 0);
  float4 a0B = *(const float4*)(xp + 32), a1B = *(const float4*)(xp + 36);
  uint4  w0B = *(const uint4*)(wp0 + 32), w1B = *(const uint4*)(wp1 + 32), w2B = *(const uint4*)(wp2 + 32);

  for (int c0 = 0; c0 < C_; c0 += 64) {
    int cA = (c0 + 64 < C_) ? c0 + 64 : c0;   // clamp: redundant reload at tail
    int cB = (c0 + 96 < C_) ? c0 + 96 : c0;
    // consume A
    {
      Frag8 af = packA(a0A, a1A);
      acc0 = __builtin_amdgcn_mfma_f32_16x16x32_bf16(af.b, asbf(w0A), acc0, 0, 0, 0);
      acc1 = __builtin_amdgcn_mfma_f32_16x16x32_bf16(af.b, asbf(w1A), acc1, 0, 0, 0);
      acc2 = __builtin_amdgcn_mfma_f32_16x16x32_bf16(af.b, asbf(w2A), acc2, 0, 0, 0);
    }
    // refill A (in flight across the rest of this iteration + next)
    a0A = *(const float4*)(xp + cA); a1A = *(const float4*)(xp + cA + 4);
    w0A = *(const uint4*)(wp0 + cA); w1A = *(const uint4*)(wp1 + cA); w2A = *(const uint4*)(wp2 + cA);
    // consume B
    {
      Frag8 af = packA(a0B, a1B);
      acc0 = __builtin_amdgcn_mfma_f32_16x16x32_bf16(af.b, asbf(w0B), acc0, 0, 0, 0);
      acc1 = __builtin_amdgcn_mfma_f32_16x16x32_bf16(af.b, asbf(w1B), acc1, 0, 0, 0);
      acc2 = __builtin_amdgcn_mfma_f32_16x16x32_bf16(af.b, asbf(w2B), acc2, 0, 0, 0);
    }
    // refill B
    a0B = *(const float4*)(xp + cB); a1B = *(const float4*)(xp + cB + 4);
    w0B = *(const uint4*)(wp0 + cB); w1B = *(const uint4*)(wp1 + cB); w2B = *(const uint4*)(wp2 + cB);
  }

  const int bb = (int)(blockIdx.x >> 8);          // 256 blocks per batch
  const int t0 = (int)(row0 - (size_t)bb * T_) + quad * 4;
  f32x4 accs[3] = {acc0, acc1, acc2};
#pragma unroll
  for (int f = 0; f < 3; ++f) {
    int gcol = wave * 48 + f * 16;
    int mat = gcol >> 6, hb = gcol & 63;
    int h = hb + q16;
    if (mat == 2) {                               // V: store transposed
      ushort4 v;
      v.x = bfbits(accs[f][0]); v.y = bfbits(accs[f][1]);
      v.z = bfbits(accs[f][2]); v.w = bfbits(accs[f][3]);
      *(ushort4*)(Vt + ((size_t)bb * H_ + h) * T_ + t0) = v;
    } else {
      float scale = (mat == 0) ? 0.125f : 1.0f;   // Q pre-scaled by 1/sqrt(64)
#pragma unroll
      for (int r = 0; r < 4; ++r) {
        size_t row = row0 + quad * 4 + r;         // C/D layout: row = quad*4+reg
        qkv[(size_t)mat * 1048576 + row * H_ + h] = bfbits(accs[f][r] * scale);
      }
    }
  }
}

// ---------------- k2: flash causal attention, in-block split-K --------------
// One block per 16-row q-tile; 4 waves take strided 64-row k-tiles with
// private (m,l,O); flash-merge through LDS at the end.
// Pipelining: next k-tile's K frags prefetched at loop top; V frags batch-
// issued before the softmax/transpose chain so PV waits are hidden.
__global__ __launch_bounds__(256) void attn(const unsigned short* __restrict__ Q,
                                            const unsigned short* __restrict__ K,
                                            const unsigned short* __restrict__ Vt,
                                            float* __restrict__ out) {
  __shared__ float ml_s[2][4][16];
  __shared__ float o_s[4][16][68];                // +4 pad
  const int lane = threadIdx.x & 63;
  const int wave = threadIdx.x >> 6;
  const int b = blockIdx.x;                       // batch
  const int tile = 255 - blockIdx.y;              // longest blocks dispatch first
  const int q16 = lane & 15, quad = lane >> 4;

  const unsigned short* Qb = Q + (size_t)b * T_ * H_;
  const unsigned short* Kb = K + (size_t)b * T_ * H_;
  const unsigned short* Vtb = Vt + (size_t)b * H_ * T_;

  const int q0 = tile * 16;
  bf16x8 qf0 = ldb8(Qb + (size_t)(q0 + q16) * H_ + quad * 8);
  bf16x8 qf1 = ldb8(Qb + (size_t)(q0 + q16) * H_ + 32 + quad * 8);

  f32x4 o0 = {0.f, 0.f, 0.f, 0.f}, o1 = o0, o2 = o0, o3 = o0;
  float m = -3.0e38f, l = 0.0f;
  const int ktiles = (tile >> 2) + 1;

  // preload K frags for first owned k-tile (in-bounds even for idle waves)
  uint4 kf[8];
  {
    const int kkb = wave * 64;
#pragma unroll
    for (int kb = 0; kb < 4; ++kb) {
      const unsigned short* kp = Kb + (size_t)(kkb + kb * 16 + q16) * H_ + quad * 8;
      kf[2 * kb]     = *(const uint4*)kp;
      kf[2 * kb + 1] = *(const uint4*)(kp + 32);
    }
  }

  for (int kt = wave; kt < ktiles; kt += 4) {
    const int kkb = kt * 64;
    const int kkn = ((kt + 4 < ktiles) ? kt + 4 : kt) * 64;
    // issue next-tile K loads (arrive during this tile's softmax+PV)
    uint4 nkf[8];
#pragma unroll
    for (int kb = 0; kb < 4; ++kb) {
      const unsigned short* kp = Kb + (size_t)(kkn + kb * 16 + q16) * H_ + quad * 8;
      nkf[2 * kb]     = *(const uint4*)kp;
      nkf[2 * kb + 1] = *(const uint4*)(kp + 32);
    }
    // batch-issue current-tile V loads (consumed after softmax chain)
    uint4 vf[8];
#pragma unroll
    for (int kb2 = 0; kb2 < 2; ++kb2) {
      const unsigned short* vp = Vtb + (size_t)q16 * T_ + kkb + kb2 * 32 + quad * 8;
#pragma unroll
      for (int j = 0; j < 4; ++j)
        vf[kb2 * 4 + j] = *(const uint4*)(vp + (size_t)(16 * j) * T_);
    }
    // QK^T (kf data arrived during previous iteration)
    f32x4 st[4];
#pragma unroll
    for (int kb = 0; kb < 4; ++kb) {
      f32x4 s = {0.f, 0.f, 0.f, 0.f};
      s = __builtin_amdgcn_mfma_f32_16x16x32_bf16(asbf(kf[2 * kb]), qf0, s, 0, 0, 0);
      s = __builtin_amdgcn_mfma_f32_16x16x32_bf16(asbf(kf[2 * kb + 1]), qf1, s, 0, 0, 0);
      st[kb] = s;
    }
    if (kt == ktiles - 1) {                       // diagonal tile: causal mask
      const int q_abs = q0 + q16;
#pragma unroll
      for (int kb = 0; kb < 4; ++kb)
#pragma unroll
        for (int r = 0; r < 4; ++r) {
          int kk_abs = kkb + kb * 16 + quad * 4 + r;
          if (kk_abs > q_abs) st[kb][r] = -3.0e38f;
        }
    }
    // row stats: per-lane q = q16; kk spread over regs (in-lane) + quads (xor)
    float mloc = fmaxf(fmaxf(st[0][0], st[0][1]), fmaxf(st[0][2], st[0][3]));
#pragma unroll
    for (int kb = 1; kb < 4; ++kb)
      mloc = fmaxf(mloc, fmaxf(fmaxf(st[kb][0], st[kb][1]), fmaxf(st[kb][2], st[kb][3])));
    mloc = fmaxf(mloc, __shfl_xor(mloc, 16));
    mloc = fmaxf(mloc, __shfl_xor(mloc, 32));
    float mnew = fmaxf(m, mloc);
    float alpha = __expf(m - mnew);
    float lsum = 0.f;
    unsigned pk[4][2];
#pragma unroll
    for (int kb = 0; kb < 4; ++kb) {
      float p0 = __expf(st[kb][0] - mnew);
      float p1 = __expf(st[kb][1] - mnew);
      float p2 = __expf(st[kb][2] - mnew);
      float p3 = __expf(st[kb][3] - mnew);
      lsum += (p0 + p1) + (p2 + p3);
      pk[kb][0] = (unsigned)bfbits(p0) | ((unsigned)bfbits(p1) << 16);
      pk[kb][1] = (unsigned)bfbits(p2) | ((unsigned)bfbits(p3) << 16);
    }
    lsum += __shfl_xor(lsum, 16);
    lsum += __shfl_xor(lsum, 32);
    l = l * alpha + lsum;
    m = mnew;
    // rescale O: row of o-frag = quad*4+reg
    float ar0 = __shfl(alpha, quad * 4 + 0);
    float ar1 = __shfl(alpha, quad * 4 + 1);
    float ar2 = __shfl(alpha, quad * 4 + 2);
    float ar3 = __shfl(alpha, quad * 4 + 3);
    o0[0] *= ar0; o0[1] *= ar1; o0[2] *= ar2; o0[3] *= ar3;
    o1[0] *= ar0; o1[1] *= ar1; o1[2] *= ar2; o1[3] *= ar3;
    o2[0] *= ar0; o2[1] *= ar1; o2[2] *= ar2; o2[3] *= ar3;
    o3[0] *= ar0; o3[1] *= ar1; o3[2] *= ar2; o3[3] *= ar3;

    // P^T (C layout) -> PV A-operand layout (K=32): half-quad exchange
    const int kbsel = quad >> 1;
    const int src0 = q16 + 32 * (quad & 1);
#pragma unroll
    for (int kb2 = 0; kb2 < 2; ++kb2) {
      int xA = __shfl((int)pk[2 * kb2][0], src0);
      int xB = __shfl((int)pk[2 * kb2 + 1][0], src0);
      int yA = __shfl((int)pk[2 * kb2][1], src0);
      int yB = __shfl((int)pk[2 * kb2 + 1][1], src0);
      int zA = __shfl((int)pk[2 * kb2][0], src0 + 16);
      int zB = __shfl((int)pk[2 * kb2 + 1][0], src0 + 16);
      int wA = __shfl((int)pk[2 * kb2][1], src0 + 16);
      int wB = __shfl((int)pk[2 * kb2 + 1][1], src0 + 16);
      Frag8 pf;
      pf.u.x = (unsigned)(kbsel ? xB : xA);
      pf.u.y = (unsigned)(kbsel ? yB : yA);
      pf.u.z = (unsigned)(kbsel ? zB : zA);
      pf.u.w = (unsigned)(kbsel ? wB : wA);
      o0 = __builtin_amdgcn_mfma_f32_16x16x32_bf16(pf.b, asbf(vf[kb2 * 4 + 0]), o0, 0, 0, 0);
      o1 = __builtin_amdgcn_mfma_f32_16x16x32_bf16(pf.b, asbf(vf[kb2 * 4 + 1]), o1, 0, 0, 0);
      o2 = __builtin_amdgcn_mfma_f32_16x16x32_bf16(pf.b, asbf(vf[kb2 * 4 + 2]), o2, 0, 0, 0);
      o3 = __builtin_amdgcn_mfma_f32_16x16x32_bf16(pf.b, asbf(vf[kb2 * 4 + 3]), o3, 0, 0, 0);
    }
    // rotate prefetched K into place
#pragma unroll
    for (int i = 0; i < 8; ++i) kf[i] = nkf[i];
  }

  // ---- flash merge across the 4 waves ----
  if (quad == 0) { ml_s[0][wave][q16] = m; ml_s[1][wave][q16] = l; }
  __syncthreads();
  float M = fmaxf(fmaxf(ml_s[0][0][q16], ml_s[0][1][q16]),
                  fmaxf(ml_s[0][2][q16], ml_s[0][3][q16]));
  float beta = __expf(m - M);                     // 0 for waves with no work
  float b0 = __shfl(beta, quad * 4 + 0);
  float b1 = __shfl(beta, quad * 4 + 1);
  float b2 = __shfl(beta, quad * 4 + 2);
  float b3 = __shfl(beta, quad * 4 + 3);
  o0[0] *= b0; o0[1] *= b1; o0[2] *= b2; o0[3] *= b3;
  o1[0] *= b0; o1[1] *= b1; o1[2] *= b2; o1[3] *= b3;
  o2[0] *= b0; o2[1] *= b1; o2[2] *= b2; o2[3] *= b3;
  o3[0] *= b0; o3[1] *= b1; o3[2] *= b2; o3[3] *= b3;
#pragma unroll
  for (int r = 0; r < 4; ++r) {
    o_s[wave][quad * 4 + r][q16 + 0]  = o0[r];
    o_s[wave][quad * 4 + r][q16 + 16] = o1[r];
    o_s[wave][quad * 4 + r][q16 + 32] = o2[r];
    o_s[wave][quad * 4 + r][q16 + 48] = o3[r];
  }
  __syncthreads();

  const int idx = threadIdx.x;
  const int row = idx >> 4;
  const int col0 = (idx & 15) * 4;
  float m0 = ml_s[0][0][row], m1 = ml_s[0][1][row];
  float m2 = ml_s[0][2][row], m3 = ml_s[0][3][row];
  float Mr = fmaxf(fmaxf(m0, m1), fmaxf(m2, m3));
  float lt = ml_s[1][0][row] * __expf(m0 - Mr) + ml_s[1][1][row] * __expf(m1 - Mr)
           + ml_s[1][2][row] * __expf(m2 - Mr) + ml_s[1][3][row] * __expf(m3 - Mr);
  float4 a0 = *(const float4*)&o_s[0][row][col0];
  float4 a1 = *(const float4*)&o_s[1][row][col0];
  float4 a2 = *(const float4*)&o_s[2][row][col0];
  float4 a3 = *(const float4*)&o_s[3][row][col0];
  float inv = 1.0f / lt;
  float4 r;
  r.x = (a0.x + a1.x + a2.x + a3.x) * inv;
  r.y = (a0.y + a1.y + a2.y + a3.y) * inv;
  r.z = (a0.z + a1.z + a2.z + a3.z) * inv;
  r.w = (a0.w + a1.w + a2.w + a3.w) * inv;
  *(float4*)(out + ((size_t)b * T_ + q0 + row) * H_ + col0) = r;
}

extern "C" void kernel_launch(void* const* d_in, const int* in_sizes, int n_in,
                              void* d_out, int out_size, void* d_ws, size_t ws_size,
                              hipStream_t stream) {
  const float* x  = (const float*)d_in[0];
  const float* Wq = (const float*)d_in[1];
  const float* Wk = (const float*)d_in[2];
  const float* Wv = (const float*)d_in[3];
  float* out = (float*)d_out;
  unsigned short* ws = (unsigned short*)d_ws;

  // ws layout (ushort units):
  //   [0, 196608)           Wb  (Q|K|V bf16 weights)
  //   [196608, +2*1048576)  Q,K bf16 [B*T][64]  (Q pre-scaled)
  //   next 1048576          Vt bf16 [B][64][T]
  unsigned short* Wb  = ws;
  unsigned short* qkv = ws + 196608;
  unsigned short* Vt  = qkv + (size_t)2 * 1048576;

  wconv<<<192, 256, 0, stream>>>(Wq, Wk, Wv, Wb);
  qkv_proj<<<1024, 256, 0, stream>>>(x, Wb, qkv, Vt);
  attn<<<dim3(4, 256), 256, 0, stream>>>(qkv, qkv + 1048576, Vt, out);
}

// Round 4
// 225.586 us; speedup vs baseline: 1.4740x; 1.4740x over previous
//
#include <hip/hip_runtime.h>
#include <hip/hip_bf16.h>

#define B_ 4
#define T_ 4096
#define C_ 1024
#define H_ 64

typedef __bf16 bf16x8 __attribute__((ext_vector_type(8)));
typedef float f32x4 __attribute__((ext_vector_type(4)));
typedef unsigned short u16x8 __attribute__((ext_vector_type(8)));

union Frag8 { uint4 u; bf16x8 b; u16x8 s; };

__device__ inline unsigned short bfbits(float f) {
  union { __hip_bfloat16 h; unsigned short u; } cv;
  cv.h = __float2bfloat16(f);
  return cv.u;
}

__device__ inline bf16x8 ldb8(const unsigned short* p) {
  Frag8 f; f.u = *(const uint4*)p; return f.b;
}

__device__ inline bf16x8 asbf(uint4 u) { Frag8 f; f.u = u; return f.b; }

__device__ inline Frag8 packA(float4 a0, float4 a1) {
  Frag8 af;
  af.s[0] = bfbits(a0.x); af.s[1] = bfbits(a0.y);
  af.s[2] = bfbits(a0.z); af.s[3] = bfbits(a0.w);
  af.s[4] = bfbits(a1.x); af.s[5] = bfbits(a1.y);
  af.s[6] = bfbits(a1.z); af.s[7] = bfbits(a1.w);
  return af;
}

// async global->LDS, 16B per lane; LDS dest = wave-uniform base + lane*16
__device__ inline void gload16(const void* g, void* l) {
  __builtin_amdgcn_global_load_lds(
      (const __attribute__((address_space(1))) unsigned int*)g,
      (__attribute__((address_space(3))) unsigned int*)l, 16, 0, 0);
}

// ---------------- k0: convert W (3 x [64,1024] fp32) to bf16 ----------------
__global__ __launch_bounds__(256) void wconv(const float* __restrict__ Wq,
                                             const float* __restrict__ Wk,
                                             const float* __restrict__ Wv,
                                             unsigned short* __restrict__ Wb) {
  int i = blockIdx.x * 256 + threadIdx.x;        // 192 blocks -> 49152 threads
  size_t e = (size_t)i * 4;                      // element index in [0, 196608)
  const float* src = (e < 65536) ? (Wq + e)
                   : (e < 131072 ? (Wk + (e - 65536)) : (Wv + (e - 131072)));
  float4 v = *(const float4*)src;
  unsigned long long o =
      (unsigned long long)bfbits(v.x)
    | ((unsigned long long)bfbits(v.y) << 16)
    | ((unsigned long long)bfbits(v.z) << 32)
    | ((unsigned long long)bfbits(v.w) << 48);
  *(unsigned long long*)(Wb + e) = o;
}

// ---------------- k1: QKV projection GEMM, m97-style LDS staging ------------
// out[m][h] = sum_c x[m][c] * W[h][c];  M=16384, K=1024, N=192 (Q|K|V)
// Block = 32 rows x 192 cols; BK=64. x-tile staged async into LDS in
// [k16grp][row] layout (A-frag ds_reads hit bank=q16*4 -> 2-way, free).
// W B-frags direct from global (L2-resident, 6 independent loads/chunk).
__global__ __launch_bounds__(256) void qkv_proj(const float* __restrict__ x,
                                                const unsigned short* __restrict__ Wb,
                                                unsigned short* __restrict__ qkv,
                                                unsigned short* __restrict__ Vt) {
  __shared__ float xs[2048];                      // 8 KB: 16B-unit u = k16*32+row
  const int lane = threadIdx.x & 63;
  const int wave = threadIdx.x >> 6;
  const int q16 = lane & 15, quad = lane >> 4;
  const size_t row0 = (size_t)blockIdx.x * 32;

  const unsigned short* wp[3];
#pragma unroll
  for (int ct = 0; ct < 3; ++ct) {
    int gcol = wave * 48 + ct * 16;               // 0..176
    wp[ct] = Wb + (size_t)(gcol >> 6) * 65536
                + (size_t)((gcol & 63) + q16) * C_ + quad * 8;
  }

  f32x4 acc[2][3] = {};
  const int srow = lane & 31, sk = lane >> 5;     // staging row / k16 half

  for (int kc = 0; kc < C_; kc += 64) {
    __syncthreads();                              // readers of prev chunk done
    // stage x-tile: wave handles issues i = 2*wave, 2*wave+1 (1 KB each)
#pragma unroll
    for (int ii = 0; ii < 2; ++ii) {
      int i = wave * 2 + ii;
      const float* gp = x + (row0 + srow) * C_ + kc + (size_t)(i * 2 + sk) * 4;
      gload16(gp, &xs[i * 256]);
    }
    // W B-frags: 6 independent global loads (overlap the staging drain)
    uint4 wf[6];
#pragma unroll
    for (int ct = 0; ct < 3; ++ct) {
      wf[ct * 2]     = *(const uint4*)(wp[ct] + kc);
      wf[ct * 2 + 1] = *(const uint4*)(wp[ct] + kc + 32);
    }
    __syncthreads();                              // staging visible
#pragma unroll
    for (int s = 0; s < 2; ++s) {
#pragma unroll
      for (int rt = 0; rt < 2; ++rt) {
        int u0 = (s * 8 + quad * 2) * 32 + rt * 16 + q16;   // 16B-unit index
        float4 a0 = *(const float4*)&xs[u0 * 4];
        float4 a1 = *(const float4*)&xs[(u0 + 32) * 4];
        Frag8 af = packA(a0, a1);
#pragma unroll
        for (int ct = 0; ct < 3; ++ct)
          acc[rt][ct] = __builtin_amdgcn_mfma_f32_16x16x32_bf16(
              af.b, asbf(wf[ct * 2 + s]), acc[rt][ct], 0, 0, 0);
      }
    }
  }

  const int bb = (int)(blockIdx.x >> 7);          // 128 blocks per batch
#pragma unroll
  for (int rt = 0; rt < 2; ++rt) {
    const int t0 = (int)(row0 - (size_t)bb * T_) + rt * 16 + quad * 4;
#pragma unroll
    for (int ct = 0; ct < 3; ++ct) {
      int gcol = wave * 48 + ct * 16;
      int mat = gcol >> 6, h = (gcol & 63) + q16;
      if (mat == 2) {                             // V: store transposed
        ushort4 v;
        v.x = bfbits(acc[rt][ct][0]); v.y = bfbits(acc[rt][ct][1]);
        v.z = bfbits(acc[rt][ct][2]); v.w = bfbits(acc[rt][ct][3]);
        *(ushort4*)(Vt + ((size_t)bb * H_ + h) * T_ + t0) = v;
      } else {
        float scale = (mat == 0) ? 0.125f : 1.0f; // Q pre-scaled by 1/sqrt(64)
#pragma unroll
        for (int r = 0; r < 4; ++r) {
          size_t row = row0 + rt * 16 + quad * 4 + r;
          qkv[(size_t)mat * 1048576 + row * H_ + h] = bfbits(acc[rt][ct][r] * scale);
        }
      }
    }
  }
}

// ---------------- k2: flash causal attention, LDS-shared K/V tiles ----------
// Block = 64 q-rows (4 waves x one 16-row q-tile); all waves sweep the same
// k-range. K-tile and V-tile staged async into LDS (swizzled: bank=q16*4).
// Every wave's causal diagonal is in the block's LAST k-tile -> uniform flow.
__global__ __launch_bounds__(256) void attn(const unsigned short* __restrict__ Q,
                                            const unsigned short* __restrict__ K,
                                            const unsigned short* __restrict__ Vt,
                                            float* __restrict__ out) {
  __shared__ unsigned short Ks[4096];             // 8 KB: u = h8*64 + krow
  __shared__ unsigned short Vs[4096];             // 8 KB: u = k8*64 + h
  const int lane = threadIdx.x & 63;
  const int wave = threadIdx.x >> 6;
  const int b = blockIdx.x;                       // batch
  const int qblk = 63 - blockIdx.y;               // longest blocks first
  const int q16 = lane & 15, quad = lane >> 4;

  const unsigned short* Qb = Q + (size_t)b * T_ * H_;
  const unsigned short* Kb = K + (size_t)b * T_ * H_;
  const unsigned short* Vtb = Vt + (size_t)b * H_ * T_;

  const int q0w = qblk * 64 + wave * 16;          // this wave's q-tile base
  bf16x8 qf0 = ldb8(Qb + (size_t)(q0w + q16) * H_ + quad * 8);
  bf16x8 qf1 = ldb8(Qb + (size_t)(q0w + q16) * H_ + 32 + quad * 8);

  f32x4 o0 = {0.f, 0.f, 0.f, 0.f}, o1 = o0, o2 = o0, o3 = o0;
  float m = -3.0e38f, l = 0.0f;
  const int ktiles = qblk + 1;

  for (int kt = 0; kt < ktiles; ++kt) {
    const int kkb = kt * 64;
    __syncthreads();                              // prev-tile readers done
    // stage K-tile and V-tile: wave handles issues 2w,2w+1 of each (1 KB ea)
#pragma unroll
    for (int ii = 0; ii < 2; ++ii) {
      int i = wave * 2 + ii;
      gload16(Kb + (size_t)(kkb + lane) * H_ + i * 8, &Ks[i * 512]);
      gload16(Vtb + (size_t)lane * T_ + kkb + i * 8, &Vs[i * 512]);
    }
    __syncthreads();                              // staging visible

    // QK^T: S^T = K Q^T; A-frag from LDS-K (bank = q16*4, conflict-free)
    f32x4 st[4];
#pragma unroll
    for (int kb = 0; kb < 4; ++kb) {
      bf16x8 ka0 = ldb8(&Ks[(quad * 64 + kb * 16 + q16) * 8]);
      bf16x8 ka1 = ldb8(&Ks[((quad + 4) * 64 + kb * 16 + q16) * 8]);
      f32x4 s = {0.f, 0.f, 0.f, 0.f};
      s = __builtin_amdgcn_mfma_f32_16x16x32_bf16(ka0, qf0, s, 0, 0, 0);
      s = __builtin_amdgcn_mfma_f32_16x16x32_bf16(ka1, qf1, s, 0, 0, 0);
      st[kb] = s;
    }
    if (kt == ktiles - 1) {                       // diagonal tile: causal mask
      const int q_abs = q0w + q16;
#pragma unroll
      for (int kb = 0; kb < 4; ++kb)
#pragma unroll
        for (int r = 0; r < 4; ++r) {
          int kk_abs = kkb + kb * 16 + quad * 4 + r;
          if (kk_abs > q_abs) st[kb][r] = -3.0e38f;
        }
    }
    // row stats: per-lane q = q16; kk spread over regs (in-lane) + quads (xor)
    float mloc = fmaxf(fmaxf(st[0][0], st[0][1]), fmaxf(st[0][2], st[0][3]));
#pragma unroll
    for (int kb = 1; kb < 4; ++kb)
      mloc = fmaxf(mloc, fmaxf(fmaxf(st[kb][0], st[kb][1]), fmaxf(st[kb][2], st[kb][3])));
    mloc = fmaxf(mloc, __shfl_xor(mloc, 16));
    mloc = fmaxf(mloc, __shfl_xor(mloc, 32));
    float mnew = fmaxf(m, mloc);
    float alpha = __expf(m - mnew);
    float lsum = 0.f;
    unsigned pk[4][2];
#pragma unroll
    for (int kb = 0; kb < 4; ++kb) {
      float p0 = __expf(st[kb][0] - mnew);
      float p1 = __expf(st[kb][1] - mnew);
      float p2 = __expf(st[kb][2] - mnew);
      float p3 = __expf(st[kb][3] - mnew);
      lsum += (p0 + p1) + (p2 + p3);
      pk[kb][0] = (unsigned)bfbits(p0) | ((unsigned)bfbits(p1) << 16);
      pk[kb][1] = (unsigned)bfbits(p2) | ((unsigned)bfbits(p3) << 16);
    }
    lsum += __shfl_xor(lsum, 16);
    lsum += __shfl_xor(lsum, 32);
    l = l * alpha + lsum;
    m = mnew;
    // rescale O: row of o-frag = quad*4+reg
    float ar0 = __shfl(alpha, quad * 4 + 0);
    float ar1 = __shfl(alpha, quad * 4 + 1);
    float ar2 = __shfl(alpha, quad * 4 + 2);
    float ar3 = __shfl(alpha, quad * 4 + 3);
    o0[0] *= ar0; o0[1] *= ar1; o0[2] *= ar2; o0[3] *= ar3;
    o1[0] *= ar0; o1[1] *= ar1; o1[2] *= ar2; o1[3] *= ar3;
    o2[0] *= ar0; o2[1] *= ar1; o2[2] *= ar2; o2[3] *= ar3;
    o3[0] *= ar0; o3[1] *= ar1; o3[2] *= ar2; o3[3] *= ar3;

    // P^T (C layout) -> PV A-operand layout (K=32): half-quad exchange
    const int kbsel = quad >> 1;
    const int src0 = q16 + 32 * (quad & 1);
#pragma unroll
    for (int kb2 = 0; kb2 < 2; ++kb2) {
      int xA = __shfl((int)pk[2 * kb2][0], src0);
      int xB = __shfl((int)pk[2 * kb2 + 1][0], src0);
      int yA = __shfl((int)pk[2 * kb2][1], src0);
      int yB = __shfl((int)pk[2 * kb2 + 1][1], src0);
      int zA = __shfl((int)pk[2 * kb2][0], src0 + 16);
      int zB = __shfl((int)pk[2 * kb2 + 1][0], src0 + 16);
      int wA = __shfl((int)pk[2 * kb2][1], src0 + 16);
      int wB = __shfl((int)pk[2 * kb2 + 1][1], src0 + 16);
      Frag8 pf;
      pf.u.x = (unsigned)(kbsel ? xB : xA);
      pf.u.y = (unsigned)(kbsel ? yB : yA);
      pf.u.z = (unsigned)(kbsel ? zB : zA);
      pf.u.w = (unsigned)(kbsel ? wB : wA);
      // V B-frags from LDS (bank = q16*4, conflict-free)
      int k8 = kb2 * 4 + quad;
      bf16x8 v0 = ldb8(&Vs[(k8 * 64 + 0  + q16) * 8]);
      bf16x8 v1 = ldb8(&Vs[(k8 * 64 + 16 + q16) * 8]);
      bf16x8 v2 = ldb8(&Vs[(k8 * 64 + 32 + q16) * 8]);
      bf16x8 v3 = ldb8(&Vs[(k8 * 64 + 48 + q16) * 8]);
      o0 = __builtin_amdgcn_mfma_f32_16x16x32_bf16(pf.b, v0, o0, 0, 0, 0);
      o1 = __builtin_amdgcn_mfma_f32_16x16x32_bf16(pf.b, v1, o1, 0, 0, 0);
      o2 = __builtin_amdgcn_mfma_f32_16x16x32_bf16(pf.b, v2, o2, 0, 0, 0);
      o3 = __builtin_amdgcn_mfma_f32_16x16x32_bf16(pf.b, v3, o3, 0, 0, 0);
    }
  }

  // finalize: each wave owns complete q-rows (full k-range) -> direct store
  float linv = 1.0f / l;
#pragma unroll
  for (int r = 0; r < 4; ++r) {
    float lr = __shfl(linv, quad * 4 + r);
    size_t rowoff = ((size_t)b * T_ + q0w + quad * 4 + r) * H_ + q16;
    out[rowoff + 0]  = o0[r] * lr;
    out[rowoff + 16] = o1[r] * lr;
    out[rowoff + 32] = o2[r] * lr;
    out[rowoff + 48] = o3[r] * lr;
  }
}

extern "C" void kernel_launch(void* const* d_in, const int* in_sizes, int n_in,
                              void* d_out, int out_size, void* d_ws, size_t ws_size,
                              hipStream_t stream) {
  const float* x  = (const float*)d_in[0];
  const float* Wq = (const float*)d_in[1];
  const float* Wk = (const float*)d_in[2];
  const float* Wv = (const float*)d_in[3];
  float* out = (float*)d_out;
  unsigned short* ws = (unsigned short*)d_ws;

  // ws layout (ushort units):
  //   [0, 196608)           Wb  (Q|K|V bf16 weights)
  //   [196608, +2*1048576)  Q,K bf16 [B*T][64]  (Q pre-scaled)
  //   next 1048576          Vt bf16 [B][64][T]
  unsigned short* Wb  = ws;
  unsigned short* qkv = ws + 196608;
  unsigned short* Vt  = qkv + (size_t)2 * 1048576;

  wconv<<<192, 256, 0, stream>>>(Wq, Wk, Wv, Wb);
  qkv_proj<<<512, 256, 0, stream>>>(x, Wb, qkv, Vt);
  attn<<<dim3(4, 64), 256, 0, stream>>>(qkv, qkv + 1048576, Vt, out);
}

// Round 5
// 194.957 us; speedup vs baseline: 1.7056x; 1.1571x over previous
//
#include <hip/hip_runtime.h>
#include <hip/hip_bf16.h>

#define B_ 4
#define T_ 4096
#define C_ 1024
#define H_ 64

typedef __bf16 bf16x8 __attribute__((ext_vector_type(8)));
typedef float f32x4 __attribute__((ext_vector_type(4)));
typedef unsigned short u16x8 __attribute__((ext_vector_type(8)));

union Frag8 { uint4 u; bf16x8 b; u16x8 s; };

__device__ inline unsigned short bfbits(float f) {
  union { __hip_bfloat16 h; unsigned short u; } cv;
  cv.h = __float2bfloat16(f);
  return cv.u;
}

__device__ inline float b2f(unsigned short u) {
  union { unsigned int i; float f; } c; c.i = ((unsigned int)u) << 16; return c.f;
}

__device__ inline bf16x8 ldb8(const unsigned short* p) {
  Frag8 f; f.u = *(const uint4*)p; return f.b;
}

__device__ inline bf16x8 asbf(uint4 u) { Frag8 f; f.u = u; return f.b; }

__device__ inline Frag8 packA(float4 a0, float4 a1) {
  Frag8 af;
  af.s[0] = bfbits(a0.x); af.s[1] = bfbits(a0.y);
  af.s[2] = bfbits(a0.z); af.s[3] = bfbits(a0.w);
  af.s[4] = bfbits(a1.x); af.s[5] = bfbits(a1.y);
  af.s[6] = bfbits(a1.z); af.s[7] = bfbits(a1.w);
  return af;
}

// async global->LDS, 16B per lane; LDS dest = wave-uniform base + lane*16
__device__ inline void gload16(const void* g, void* l) {
  __builtin_amdgcn_global_load_lds(
      (const __attribute__((address_space(1))) unsigned int*)g,
      (__attribute__((address_space(3))) unsigned int*)l, 16, 0, 0);
}

// ---------------- k0: convert W (3 x [64,1024] fp32) to bf16 ----------------
__global__ __launch_bounds__(256) void wconv(const float* __restrict__ Wq,
                                             const float* __restrict__ Wk,
                                             const float* __restrict__ Wv,
                                             unsigned short* __restrict__ Wb) {
  int i = blockIdx.x * 256 + threadIdx.x;
  size_t e = (size_t)i * 4;
  const float* src = (e < 65536) ? (Wq + e)
                   : (e < 131072 ? (Wk + (e - 65536)) : (Wv + (e - 131072)));
  float4 v = *(const float4*)src;
  unsigned long long o =
      (unsigned long long)bfbits(v.x)
    | ((unsigned long long)bfbits(v.y) << 16)
    | ((unsigned long long)bfbits(v.z) << 32)
    | ((unsigned long long)bfbits(v.w) << 48);
  *(unsigned long long*)(Wb + e) = o;
}

// ---------------- k1: QKV projection GEMM, coalesced LDS staging ------------
// Block = 32 rows x 192 cols; BK=64. x-tile staged async into LDS row-major;
// GLOBAL side carries a 32B-superchunk XOR swizzle (stays within cache lines,
// so coalescing is preserved: 4 rows x 256B contiguous per 1KB issue) so the
// A-frag ds_read_b128s spread over bank groups (<=2-way).
__global__ __launch_bounds__(256) void qkv_proj(const float* __restrict__ x,
                                                const unsigned short* __restrict__ Wb,
                                                unsigned short* __restrict__ qkv,
                                                unsigned short* __restrict__ Vt) {
  __shared__ float xs[2048];                      // 32 rows x 64 f32 (swizzled)
  const int lane = threadIdx.x & 63;
  const int wave = threadIdx.x >> 6;
  const int q16 = lane & 15, quad = lane >> 4;
  const size_t row0 = (size_t)blockIdx.x * 32;

  const unsigned short* wp[3];
#pragma unroll
  for (int ct = 0; ct < 3; ++ct) {
    int gcol = wave * 48 + ct * 16;               // 0..176
    wp[ct] = Wb + (size_t)(gcol >> 6) * 65536
                + (size_t)((gcol & 63) + q16) * C_ + quad * 8;
  }

  // staging address pieces (constant across K-chunks)
  const int sr = (lane >> 4);                     // row-within-issue-group
  const int sc_pos = lane & 15;                   // stored 16B-chunk position
  f32x4 acc[2][3] = {};

  for (int kc = 0; kc < C_; kc += 64) {
    __syncthreads();                              // readers of prev chunk done
#pragma unroll
    for (int ii = 0; ii < 2; ++ii) {
      int i = wave * 2 + ii;                      // issue 0..7
      int r = i * 4 + sr;                         // tile row 0..31
      int sg = (sc_pos >> 1) ^ (r & 7);           // swizzled global superchunk
      const float* gp = x + (row0 + r) * C_ + kc + sg * 8 + (sc_pos & 1) * 4;
      gload16(gp, &xs[i * 256]);
    }
    // W B-frags: 6 independent L2 loads (overlap staging drain)
    uint4 wf[6];
#pragma unroll
    for (int ct = 0; ct < 3; ++ct) {
      wf[ct * 2]     = *(const uint4*)(wp[ct] + kc);
      wf[ct * 2 + 1] = *(const uint4*)(wp[ct] + kc + 32);
    }
    __syncthreads();                              // staging visible
#pragma unroll
    for (int s = 0; s < 2; ++s) {
#pragma unroll
      for (int rt = 0; rt < 2; ++rt) {
        int r = rt * 16 + q16;
        int p = ((s * 4 + quad) ^ (r & 7)) * 8;   // un-swizzle superchunk
        const float* ap = &xs[r * 64 + p];
        float4 a0 = *(const float4*)ap;
        float4 a1 = *(const float4*)(ap + 4);
        Frag8 af = packA(a0, a1);
#pragma unroll
        for (int ct = 0; ct < 3; ++ct)
          acc[rt][ct] = __builtin_amdgcn_mfma_f32_16x16x32_bf16(
              af.b, asbf(wf[ct * 2 + s]), acc[rt][ct], 0, 0, 0);
      }
    }
  }

  const int bb = (int)(blockIdx.x >> 7);          // 128 blocks per batch
#pragma unroll
  for (int rt = 0; rt < 2; ++rt) {
    const int t0 = (int)(row0 - (size_t)bb * T_) + rt * 16 + quad * 4;
#pragma unroll
    for (int ct = 0; ct < 3; ++ct) {
      int gcol = wave * 48 + ct * 16;
      int mat = gcol >> 6, h = (gcol & 63) + q16;
      if (mat == 2) {                             // V: store transposed
        ushort4 v;
        v.x = bfbits(acc[rt][ct][0]); v.y = bfbits(acc[rt][ct][1]);
        v.z = bfbits(acc[rt][ct][2]); v.w = bfbits(acc[rt][ct][3]);
        *(ushort4*)(Vt + ((size_t)bb * H_ + h) * T_ + t0) = v;
      } else {
        float scale = (mat == 0) ? 0.125f : 1.0f; // Q pre-scaled by 1/sqrt(64)
#pragma unroll
        for (int r = 0; r < 4; ++r) {
          size_t row = row0 + rt * 16 + quad * 4 + r;
          qkv[(size_t)mat * 1048576 + row * H_ + h] = bfbits(acc[rt][ct][r] * scale);
        }
      }
    }
  }
}

// ---------------- k2: flash attention, flat (q-tile x k-chunk) + partials ---
// grid (1024, 8): x = global q-tile (b*256+qtl), y = 512-row k-chunk.
// Invalid chunks exit. 4 waves split the chunk's <=8 k-tiles (2 each),
// in-block LDS merge, write UNNORMALIZED partial (m,l fp32 + O bf16) to ws.
__global__ __launch_bounds__(256) void attn(const unsigned short* __restrict__ Q,
                                            const unsigned short* __restrict__ K,
                                            const unsigned short* __restrict__ Vt,
                                            float* __restrict__ part) {
  const int qt = blockIdx.x;                      // 0..1023
  const int qtl = qt & 255, b = qt >> 8;
  const int ki = (qtl >> 2) + 1;                  // total 64-row k-tiles
  const int c = blockIdx.y;
  if (c * 8 >= ki) return;
  const int e = (ki < c * 8 + 8) ? ki : c * 8 + 8;

  __shared__ float ml_s[2][4][16];
  __shared__ float o_s[4][16][68];
  const int lane = threadIdx.x & 63;
  const int wave = threadIdx.x >> 6;
  const int q16 = lane & 15, quad = lane >> 4;

  const unsigned short* Qb = Q + (size_t)b * T_ * H_;
  const unsigned short* Kb = K + (size_t)b * T_ * H_;
  const unsigned short* Vtb = Vt + (size_t)b * H_ * T_;

  const int q0 = qtl * 16;
  bf16x8 qf0 = ldb8(Qb + (size_t)(q0 + q16) * H_ + quad * 8);
  bf16x8 qf1 = ldb8(Qb + (size_t)(q0 + q16) * H_ + 32 + quad * 8);

  f32x4 o0 = {0.f, 0.f, 0.f, 0.f}, o1 = o0, o2 = o0, o3 = o0;
  float m = -3.0e38f, l = 0.0f;

  for (int tl = c * 8 + wave; tl < e; tl += 4) {
    const int kkb = tl * 64;
    // batch-issue V then K loads (V consumed last; K first)
    uint4 vf[8];
#pragma unroll
    for (int kb2 = 0; kb2 < 2; ++kb2) {
      const unsigned short* vp = Vtb + (size_t)q16 * T_ + kkb + kb2 * 32 + quad * 8;
#pragma unroll
      for (int j = 0; j < 4; ++j)
        vf[kb2 * 4 + j] = *(const uint4*)(vp + (size_t)(16 * j) * T_);
    }
    uint4 kf[8];
#pragma unroll
    for (int kb = 0; kb < 4; ++kb) {
      const unsigned short* kp = Kb + (size_t)(kkb + kb * 16 + q16) * H_ + quad * 8;
      kf[2 * kb]     = *(const uint4*)kp;
      kf[2 * kb + 1] = *(const uint4*)(kp + 32);
    }
    // QK^T: S^T = K Q^T  (C layout: kk=quad*4+reg, q=lane&15)
    f32x4 st[4];
#pragma unroll
    for (int kb = 0; kb < 4; ++kb) {
      f32x4 s = {0.f, 0.f, 0.f, 0.f};
      s = __builtin_amdgcn_mfma_f32_16x16x32_bf16(asbf(kf[2 * kb]), qf0, s, 0, 0, 0);
      s = __builtin_amdgcn_mfma_f32_16x16x32_bf16(asbf(kf[2 * kb + 1]), qf1, s, 0, 0, 0);
      st[kb] = s;
    }
    if (tl == ki - 1) {                           // diagonal tile: causal mask
      const int q_abs = q0 + q16;
#pragma unroll
      for (int kb = 0; kb < 4; ++kb)
#pragma unroll
        for (int r = 0; r < 4; ++r) {
          int kk_abs = kkb + kb * 16 + quad * 4 + r;
          if (kk_abs > q_abs) st[kb][r] = -3.0e38f;
        }
    }
    // online softmax
    float mloc = fmaxf(fmaxf(st[0][0], st[0][1]), fmaxf(st[0][2], st[0][3]));
#pragma unroll
    for (int kb = 1; kb < 4; ++kb)
      mloc = fmaxf(mloc, fmaxf(fmaxf(st[kb][0], st[kb][1]), fmaxf(st[kb][2], st[kb][3])));
    mloc = fmaxf(mloc, __shfl_xor(mloc, 16));
    mloc = fmaxf(mloc, __shfl_xor(mloc, 32));
    float mnew = fmaxf(m, mloc);
    float alpha = __expf(m - mnew);
    float lsum = 0.f;
    unsigned pk[4][2];
#pragma unroll
    for (int kb = 0; kb < 4; ++kb) {
      float p0 = __expf(st[kb][0] - mnew);
      float p1 = __expf(st[kb][1] - mnew);
      float p2 = __expf(st[kb][2] - mnew);
      float p3 = __expf(st[kb][3] - mnew);
      lsum += (p0 + p1) + (p2 + p3);
      pk[kb][0] = (unsigned)bfbits(p0) | ((unsigned)bfbits(p1) << 16);
      pk[kb][1] = (unsigned)bfbits(p2) | ((unsigned)bfbits(p3) << 16);
    }
    lsum += __shfl_xor(lsum, 16);
    lsum += __shfl_xor(lsum, 32);
    l = l * alpha + lsum;
    m = mnew;
    float ar0 = __shfl(alpha, quad * 4 + 0);
    float ar1 = __shfl(alpha, quad * 4 + 1);
    float ar2 = __shfl(alpha, quad * 4 + 2);
    float ar3 = __shfl(alpha, quad * 4 + 3);
    o0[0] *= ar0; o0[1] *= ar1; o0[2] *= ar2; o0[3] *= ar3;
    o1[0] *= ar0; o1[1] *= ar1; o1[2] *= ar2; o1[3] *= ar3;
    o2[0] *= ar0; o2[1] *= ar1; o2[2] *= ar2; o2[3] *= ar3;
    o3[0] *= ar0; o3[1] *= ar1; o3[2] *= ar2; o3[3] *= ar3;

    // P^T (C layout) -> PV A-operand layout (K=32): half-quad exchange
    const int kbsel = quad >> 1;
    const int src0 = q16 + 32 * (quad & 1);
#pragma unroll
    for (int kb2 = 0; kb2 < 2; ++kb2) {
      int xA = __shfl((int)pk[2 * kb2][0], src0);
      int xB = __shfl((int)pk[2 * kb2 + 1][0], src0);
      int yA = __shfl((int)pk[2 * kb2][1], src0);
      int yB = __shfl((int)pk[2 * kb2 + 1][1], src0);
      int zA = __shfl((int)pk[2 * kb2][0], src0 + 16);
      int zB = __shfl((int)pk[2 * kb2 + 1][0], src0 + 16);
      int wA = __shfl((int)pk[2 * kb2][1], src0 + 16);
      int wB = __shfl((int)pk[2 * kb2 + 1][1], src0 + 16);
      Frag8 pf;
      pf.u.x = (unsigned)(kbsel ? xB : xA);
      pf.u.y = (unsigned)(kbsel ? yB : yA);
      pf.u.z = (unsigned)(kbsel ? zB : zA);
      pf.u.w = (unsigned)(kbsel ? wB : wA);
      o0 = __builtin_amdgcn_mfma_f32_16x16x32_bf16(pf.b, asbf(vf[kb2 * 4 + 0]), o0, 0, 0, 0);
      o1 = __builtin_amdgcn_mfma_f32_16x16x32_bf16(pf.b, asbf(vf[kb2 * 4 + 1]), o1, 0, 0, 0);
      o2 = __builtin_amdgcn_mfma_f32_16x16x32_bf16(pf.b, asbf(vf[kb2 * 4 + 2]), o2, 0, 0, 0);
      o3 = __builtin_amdgcn_mfma_f32_16x16x32_bf16(pf.b, asbf(vf[kb2 * 4 + 3]), o3, 0, 0, 0);
    }
  }

  // ---- in-block flash merge across the 4 waves ----
  if (quad == 0) { ml_s[0][wave][q16] = m; ml_s[1][wave][q16] = l; }
  __syncthreads();
  float M = fmaxf(fmaxf(ml_s[0][0][q16], ml_s[0][1][q16]),
                  fmaxf(ml_s[0][2][q16], ml_s[0][3][q16]));
  float beta = __expf(m - M);                     // 0 for idle waves
  float b0 = __shfl(beta, quad * 4 + 0);
  float b1 = __shfl(beta, quad * 4 + 1);
  float b2 = __shfl(beta, quad * 4 + 2);
  float b3 = __shfl(beta, quad * 4 + 3);
  o0[0] *= b0; o0[1] *= b1; o0[2] *= b2; o0[3] *= b3;
  o1[0] *= b0; o1[1] *= b1; o1[2] *= b2; o1[3] *= b3;
  o2[0] *= b0; o2[1] *= b1; o2[2] *= b2; o2[3] *= b3;
  o3[0] *= b0; o3[1] *= b1; o3[2] *= b2; o3[3] *= b3;
#pragma unroll
  for (int r = 0; r < 4; ++r) {
    o_s[wave][quad * 4 + r][q16 + 0]  = o0[r];
    o_s[wave][quad * 4 + r][q16 + 16] = o1[r];
    o_s[wave][quad * 4 + r][q16 + 32] = o2[r];
    o_s[wave][quad * 4 + r][q16 + 48] = o3[r];
  }
  __syncthreads();

  const int t = threadIdx.x;
  const int row = t >> 4;
  const int col0 = (t & 15) * 4;
  float m0 = ml_s[0][0][row], m1 = ml_s[0][1][row];
  float m2 = ml_s[0][2][row], m3 = ml_s[0][3][row];
  float Mr = fmaxf(fmaxf(m0, m1), fmaxf(m2, m3));
  float lt = ml_s[1][0][row] * __expf(m0 - Mr) + ml_s[1][1][row] * __expf(m1 - Mr)
           + ml_s[1][2][row] * __expf(m2 - Mr) + ml_s[1][3][row] * __expf(m3 - Mr);
  float4 a0 = *(const float4*)&o_s[0][row][col0];
  float4 a1 = *(const float4*)&o_s[1][row][col0];
  float4 a2 = *(const float4*)&o_s[2][row][col0];
  float4 a3 = *(const float4*)&o_s[3][row][col0];
  // write unnormalized partial: O bf16 [16][64], then m[16], l[16] fp32
  float* P = part + (size_t)(qt * 8 + c) * 544;
  ushort4 ov;
  ov.x = bfbits(a0.x + a1.x + a2.x + a3.x);
  ov.y = bfbits(a0.y + a1.y + a2.y + a3.y);
  ov.z = bfbits(a0.z + a1.z + a2.z + a3.z);
  ov.w = bfbits(a0.w + a1.w + a2.w + a3.w);
  *((ushort4*)P + t) = ov;
  if ((t & 15) == 0) { P[512 + row] = Mr; P[528 + row] = lt; }
}

// ---------------- k3: merge <=8 partials per q-tile, normalize, store -------
__global__ __launch_bounds__(256) void attn_merge(const float* __restrict__ part,
                                                  float* __restrict__ out) {
  const int qt = blockIdx.x;                      // 0..1023
  const int qtl = qt & 255, b = qt >> 8;
  const int ki = (qtl >> 2) + 1;
  const int nch = (ki + 7) >> 3;
  const int t = threadIdx.x;
  const int row = t >> 4, col0 = (t & 15) * 4;
  const float* P0 = part + (size_t)qt * 8 * 544;
  float M = -3.0e38f;
  for (int c2 = 0; c2 < nch; ++c2) M = fmaxf(M, P0[c2 * 544 + 512 + row]);
  float L = 0.f;
  float ax = 0.f, ay = 0.f, az = 0.f, aw = 0.f;
  for (int c2 = 0; c2 < nch; ++c2) {
    const float* P = P0 + c2 * 544;
    float w = __expf(P[512 + row] - M);
    L += w * P[528 + row];
    ushort4 ov = *((const ushort4*)P + t);
    ax += w * b2f(ov.x); ay += w * b2f(ov.y);
    az += w * b2f(ov.z); aw += w * b2f(ov.w);
  }
  float inv = 1.0f / L;
  float4 r = {ax * inv, ay * inv, az * inv, aw * inv};
  *(float4*)(out + ((size_t)b * T_ + qtl * 16 + row) * H_ + col0) = r;
}

extern "C" void kernel_launch(void* const* d_in, const int* in_sizes, int n_in,
                              void* d_out, int out_size, void* d_ws, size_t ws_size,
                              hipStream_t stream) {
  const float* x  = (const float*)d_in[0];
  const float* Wq = (const float*)d_in[1];
  const float* Wk = (const float*)d_in[2];
  const float* Wv = (const float*)d_in[3];
  float* out = (float*)d_out;
  unsigned short* ws = (unsigned short*)d_ws;

  // ws layout (ushort units):
  //   [0, 196608)           Wb  (Q|K|V bf16 weights)
  //   [196608, +2*1048576)  Q,K bf16 [B*T][64]  (Q pre-scaled)
  //   next 1048576          Vt bf16 [B][64][T]
  //   next (float region)   partials: 8192 x 544 fp32 words (~17.8 MB)
  // total ~24.3 MB
  unsigned short* Wb  = ws;
  unsigned short* qkv = ws + 196608;
  unsigned short* Vt  = qkv + (size_t)2 * 1048576;
  float* part = (float*)(ws + 196608 + (size_t)3 * 1048576);

  wconv<<<192, 256, 0, stream>>>(Wq, Wk, Wv, Wb);
  qkv_proj<<<512, 256, 0, stream>>>(x, Wb, qkv, Vt);
  attn<<<dim3(1024, 8), 256, 0, stream>>>(qkv, qkv + 1048576, Vt, part);
  attn_merge<<<1024, 256, 0, stream>>>(part, out);
}